// Round 1
// baseline (170.474 us; speedup 1.0000x reference)
//
#include <hip/hip_runtime.h>

// Shapes: N=8, M=2048 -> 16384 rows; D=128, L=128.
// out0 h: (16384,128) fp32; out1 edge: (8,2048,2048) = e[row] broadcast.
//
// R11 model: overhead 123.5 + prep 2 + compute ~10.5 + broadcast ~22.
// R12 theory: compute is L2-BW bound on weight re-reads (1024 blocks x
// 160KB = 164 MB L2). Untested cell: FUSED edge write x 32-rows/block x
// weights-held-in-registers across row-tiles.
//   - 512 blocks x 32 rows: weight L2 traffic halves (82 MB, -2.4us)
//   - edge rows written at end of compute block: one launch + one drain
//     fewer, no e_ws round-trip
// Predict: fused kernel ~26-29us, total 152-155us.

typedef short short8 __attribute__((ext_vector_type(8)));
typedef float floatx4 __attribute__((ext_vector_type(4)));

__device__ __forceinline__ short f2bf(float f) {
    union { float f; unsigned u; } v; v.f = f;
    unsigned r = v.u + 0x7fffu + ((v.u >> 16) & 1u);   // RNE
    return (short)(r >> 16);
}

// d_ws: shorts in MFMA-fragment order (unchanged from R8):
//   W1S at 0      (64KB): idx = ((ct*4+k)*64 + l)*8 + j, ct 0..15, k 0..3
//   W2S at 32768  (64KB): idx = ((ct*8+k)*64 + l)*8 + j, ct 0..7,  k 0..7
//   WES at 65536  (32KB): idx = ((ct*4+k)*64 + l)*8 + j, ct 0..7,  k 0..3
// Requires ws_size >= 163840 bytes.
__global__ __launch_bounds__(256)
void prep_weights(const float* __restrict__ w1n, const float* __restrict__ w2n,
                  const float* __restrict__ w1e, short* __restrict__ ws)
{
    const int id = blockIdx.x * 256 + threadIdx.x;   // 0..81919
    const int j = id & 7;
    if (id < 32768) {
        const int g = id >> 3, l = g & 63, ctk = g >> 6;
        const int ct = ctk >> 2, k = ctk & 3;
        const int kg = k * 32 + (l >> 4) * 8 + j;
        ws[id] = f2bf(w1n[kg * 256 + ct * 16 + (l & 15)]);
    } else if (id < 65536) {
        const int g = (id - 32768) >> 3, l = g & 63, ctk = g >> 6;
        const int ct = ctk >> 3, k = ctk & 7;
        const int kg = k * 32 + (l >> 4) * 8 + j;
        ws[id] = f2bf(w2n[kg * 128 + ct * 16 + (l & 15)]);
    } else {
        const int g = (id - 65536) >> 3, l = g & 63, ctk = g >> 6;
        const int ct = ctk >> 2, k = ctk & 3;
        const int kg = k * 32 + (l >> 4) * 8 + j;
        ws[id] = f2bf(w1e[kg * 128 + ct * 16 + (l & 15)]
                      + w1e[(kg + 128) * 128 + ct * 16 + (l & 15)]);
    }
}

#define TPB 256
#define RPB 32           // rows per block (2 row-tiles of 16)
#define H1_STRIDE 264    // 256 + 8 pad (proven conflict-free)
#define HB_STRIDE 136    // 128 + 8 pad

// MFMA 16x16x32 bf16 lane mapping:
//   A: lane holds A[m = lane&15][k = (lane>>4)*8 + j], j=0..7
//   B: lane holds B[k = (lane>>4)*8 + j][n = lane&15]
//   C/D: reg r holds D[row = (lane>>4)*4 + r][col = lane&15]
__global__ __launch_bounds__(TPB, 2)
void node_edge(const float* __restrict__ x,
               const float* __restrict__ b1n, const float* __restrict__ b2n,
               const float* __restrict__ b1e,
               const float* __restrict__ w2e, const float* __restrict__ b2e,
               const short* __restrict__ wt,
               float* __restrict__ h_out, float* __restrict__ edge_out)
{
    __shared__ short h1s[RPB * H1_STRIDE];   // 16.9 KB
    __shared__ short hbs[RPB * HB_STRIDE];   // 8.7 KB
    __shared__ float partial[4][RPB];
    __shared__ float es_s[RPB];

    const int t = threadIdx.x;
    const int w = t >> 6;          // wave 0..3
    const int l = t & 63;
    const int l15 = l & 15;
    const int quad = l >> 4;
    const int row0 = blockIdx.x * RPB;   // 512 blocks, 32 rows each

    const short* __restrict__ W2S = wt + 32768;
    const short* __restrict__ WES = wt + 65536;

    // ---- stage 1: h1 = relu(X @ W1n + b1n) ----
    // Weight fragments loaded ONCE into registers, reused across both
    // row-tiles (they don't fit L1; re-reading from L2 was 4.8us of the
    // old kernel's time). 16 short8 = 64 VGPR, all indices unroll-static.
    short8 wf1[16];
#pragma unroll
    for (int ci = 0; ci < 4; ++ci)
#pragma unroll
        for (int k = 0; k < 4; ++k)
            wf1[ci * 4 + k] =
                *(const short8*)(wt + (((4 * w + ci) * 4 + k) * 64 + l) * 8);

#pragma unroll
    for (int rt = 0; rt < 2; ++rt) {
        // x -> A-fragments directly (verified R9/R10)
        short8 a1[4];
#pragma unroll
        for (int k = 0; k < 4; ++k) {
            const float* p = x + (size_t)(row0 + rt * 16 + l15) * 128 + k * 32 + quad * 8;
            const float4 v0 = *(const float4*)p;
            const float4 v1 = *(const float4*)(p + 4);
            short8 a;
            a[0] = f2bf(v0.x); a[1] = f2bf(v0.y); a[2] = f2bf(v0.z); a[3] = f2bf(v0.w);
            a[4] = f2bf(v1.x); a[5] = f2bf(v1.y); a[6] = f2bf(v1.z); a[7] = f2bf(v1.w);
            a1[k] = a;
        }
#pragma unroll
        for (int ci = 0; ci < 4; ++ci) {
            const int ct = 4 * w + ci;
            const float b = b1n[ct * 16 + l15];
            floatx4 acc = (floatx4){b, b, b, b};
#pragma unroll
            for (int k = 0; k < 4; ++k)
                acc = __builtin_amdgcn_mfma_f32_16x16x32_bf16(a1[k], wf1[ci * 4 + k], acc, 0, 0, 0);
#pragma unroll
            for (int r = 0; r < 4; ++r)
                h1s[(rt * 16 + quad * 4 + r) * H1_STRIDE + ct * 16 + l15] =
                    f2bf(fmaxf(acc[r], 0.f));
        }
    }
    __syncthreads();

    // ---- stage 2: h = h1 @ W2n + b2n ----
    short8 wf2[16];
#pragma unroll
    for (int ci = 0; ci < 2; ++ci)
#pragma unroll
        for (int k = 0; k < 8; ++k)
            wf2[ci * 8 + k] =
                *(const short8*)(W2S + (((2 * w + ci) * 8 + k) * 64 + l) * 8);

#pragma unroll
    for (int rt = 0; rt < 2; ++rt) {
        short8 a2[8];
#pragma unroll
        for (int k = 0; k < 8; ++k)
            a2[k] = *(const short8*)&h1s[(rt * 16 + l15) * H1_STRIDE + k * 32 + quad * 8];
#pragma unroll
        for (int ci = 0; ci < 2; ++ci) {
            const int ct = 2 * w + ci;
            const float b = b2n[ct * 16 + l15];
            floatx4 acc = (floatx4){b, b, b, b};
#pragma unroll
            for (int k = 0; k < 8; ++k)
                acc = __builtin_amdgcn_mfma_f32_16x16x32_bf16(a2[k], wf2[ci * 8 + k], acc, 0, 0, 0);
#pragma unroll
            for (int r = 0; r < 4; ++r) {
                const int row = rt * 16 + quad * 4 + r;
                h_out[(size_t)(row0 + row) * 128 + ct * 16 + l15] = acc[r];
                hbs[row * HB_STRIDE + ct * 16 + l15] = f2bf(acc[r]);
            }
        }
    }
    __syncthreads();

    // ---- stage 3+4: t1 = relu(h @ WE + b1e); e = (t1 . w2e + b2e)/2048 ----
    short8 wfe[8];
#pragma unroll
    for (int ci = 0; ci < 2; ++ci)
#pragma unroll
        for (int k = 0; k < 4; ++k)
            wfe[ci * 4 + k] =
                *(const short8*)(WES + (((2 * w + ci) * 4 + k) * 64 + l) * 8);

#pragma unroll
    for (int rt = 0; rt < 2; ++rt) {
        short8 a3[4];
#pragma unroll
        for (int k = 0; k < 4; ++k)
            a3[k] = *(const short8*)&hbs[(rt * 16 + l15) * HB_STRIDE + k * 32 + quad * 8];

        float p[4] = {0.f, 0.f, 0.f, 0.f};
#pragma unroll
        for (int ci = 0; ci < 2; ++ci) {
            const int ct = 2 * w + ci;
            const float b = b1e[ct * 16 + l15];
            floatx4 acc = (floatx4){b, b, b, b};
#pragma unroll
            for (int k = 0; k < 4; ++k)
                acc = __builtin_amdgcn_mfma_f32_16x16x32_bf16(a3[k], wfe[ci * 4 + k], acc, 0, 0, 0);
            const float wv = w2e[ct * 16 + l15];
#pragma unroll
            for (int r = 0; r < 4; ++r)
                p[r] += fmaxf(acc[r], 0.f) * wv;
        }
#pragma unroll
        for (int off = 8; off >= 1; off >>= 1)
#pragma unroll
            for (int r = 0; r < 4; ++r)
                p[r] += __shfl_xor(p[r], off, 64);
        if (l15 == 0) {
#pragma unroll
            for (int r = 0; r < 4; ++r)
                partial[w][rt * 16 + quad * 4 + r] = p[r];
        }
    }
    __syncthreads();
    if (t < RPB) {
        es_s[t] = (partial[0][t] + partial[1][t] + partial[2][t]
                   + partial[3][t] + b2e[0]) * (1.0f / 2048.0f);
    }
    __syncthreads();

    // ---- fused edge broadcast: 32 rows x 8KB = 256KB/block, coalesced
    // float4 streams. Shares the end-of-kernel drain with the h stores. ----
    floatx4* __restrict__ e4 = (floatx4*)(edge_out + (size_t)row0 * 2048);
#pragma unroll 4
    for (int r = 0; r < RPB; ++r) {
        const float v = es_s[r];
        const floatx4 a = (floatx4){v, v, v, v};
        e4[r * 512 + t] = a;
        e4[r * 512 + t + 256] = a;
    }
}

extern "C" void kernel_launch(void* const* d_in, const int* in_sizes, int n_in,
                              void* d_out, int out_size, void* d_ws, size_t ws_size,
                              hipStream_t stream) {
    const float* x   = (const float*)d_in[0];
    const float* w1n = (const float*)d_in[1];
    const float* b1n = (const float*)d_in[2];
    const float* w2n = (const float*)d_in[3];
    const float* b2n = (const float*)d_in[4];
    const float* w1e = (const float*)d_in[5];
    const float* b1e = (const float*)d_in[6];
    const float* w2e = (const float*)d_in[7];
    const float* b2e = (const float*)d_in[8];

    float* h_out    = (float*)d_out;                              // (8,2048,128)
    float* edge_out = (float*)d_out + (size_t)8 * 2048 * 128;     // (8,2048,2048)
    short* wt       = (short*)d_ws;                               // 160 KB swizzled bf16 weights

    prep_weights<<<dim3(320), dim3(256), 0, stream>>>(w1n, w2n, w1e, wt);
    node_edge<<<dim3(512), dim3(TPB), 0, stream>>>(
        x, b1n, b2n, b1e, w2e, b2e, wt, h_out, edge_out);
}

// Round 2
// 155.993 us; speedup vs baseline: 1.0928x; 1.0928x over previous
//
#include <hip/hip_runtime.h>

// Shapes: N=8, M=2048 -> 16384 rows; D=128, L=128.
// out0 h: (16384,128) fp32; out1 edge: (8,2048,2048) = e[row] broadcast.
//
// R12 post-mortem: fusing + weights-held-in-registers at occupancy 2
// REGRESSED (158->170.5): compute phase ~doubled. Occupancy 4 (16 waves/CU)
// is worth more than the 2.4us L2-weight saving via register residency.
// R13: split structure (proven), but RPB=32 / grid 512 with loop order
// {load weight frag once -> MFMA into both row-tiles}. Weight L2 traffic
// halves (164->82MB) with no sustained register cost; occupancy stays 4.
// Predict: compute 10.5->~8us, total ~155us.

typedef short short8 __attribute__((ext_vector_type(8)));
typedef float floatx4 __attribute__((ext_vector_type(4)));

__device__ __forceinline__ short f2bf(float f) {
    union { float f; unsigned u; } v; v.f = f;
    unsigned r = v.u + 0x7fffu + ((v.u >> 16) & 1u);   // RNE
    return (short)(r >> 16);
}

// d_ws: shorts in MFMA-fragment order (unchanged from R8):
//   W1S at 0      (64KB): idx = ((ct*4+k)*64 + l)*8 + j, ct 0..15, k 0..3
//   W2S at 32768  (64KB): idx = ((ct*8+k)*64 + l)*8 + j, ct 0..7,  k 0..7
//   WES at 65536  (32KB): idx = ((ct*4+k)*64 + l)*8 + j, ct 0..7,  k 0..3
//   float es[16384] at byte 163840 (64KB)
// Requires ws_size >= 229376 bytes.
__global__ __launch_bounds__(256)
void prep_weights(const float* __restrict__ w1n, const float* __restrict__ w2n,
                  const float* __restrict__ w1e, short* __restrict__ ws)
{
    const int id = blockIdx.x * 256 + threadIdx.x;   // 0..81919
    const int j = id & 7;
    if (id < 32768) {
        const int g = id >> 3, l = g & 63, ctk = g >> 6;
        const int ct = ctk >> 2, k = ctk & 3;
        const int kg = k * 32 + (l >> 4) * 8 + j;
        ws[id] = f2bf(w1n[kg * 256 + ct * 16 + (l & 15)]);
    } else if (id < 65536) {
        const int g = (id - 32768) >> 3, l = g & 63, ctk = g >> 6;
        const int ct = ctk >> 3, k = ctk & 7;
        const int kg = k * 32 + (l >> 4) * 8 + j;
        ws[id] = f2bf(w2n[kg * 128 + ct * 16 + (l & 15)]);
    } else {
        const int g = (id - 65536) >> 3, l = g & 63, ctk = g >> 6;
        const int ct = ctk >> 2, k = ctk & 3;
        const int kg = k * 32 + (l >> 4) * 8 + j;
        ws[id] = f2bf(w1e[kg * 128 + ct * 16 + (l & 15)]
                      + w1e[(kg + 128) * 128 + ct * 16 + (l & 15)]);
    }
}

#define TPB 256
#define RPB 32           // 2 row-tiles of 16 per block
#define H1_STRIDE 264    // 256 + 8 pad (proven conflict-free)
#define HB_STRIDE 136    // 128 + 8 pad

// MFMA 16x16x32 bf16 lane mapping:
//   A: lane holds A[m = lane&15][k = (lane>>4)*8 + j], j=0..7
//   B: lane holds B[k = (lane>>4)*8 + j][n = lane&15]
//   C/D: reg r holds D[row = (lane>>4)*4 + r][col = lane&15]
__global__ __launch_bounds__(TPB, 4)
void node_compute(const float* __restrict__ x,
                  const float* __restrict__ b1n, const float* __restrict__ b2n,
                  const float* __restrict__ b1e,
                  const float* __restrict__ w2e, const float* __restrict__ b2e,
                  const short* __restrict__ wt,
                  float* __restrict__ h_out, float* __restrict__ e_ws)
{
    __shared__ short h1s[RPB * H1_STRIDE];   // 16.9 KB
    __shared__ short hbs[RPB * HB_STRIDE];   // 8.7 KB
    __shared__ float partial[4][RPB];

    const int t = threadIdx.x;
    const int w = t >> 6;          // wave 0..3
    const int l = t & 63;
    const int l15 = l & 15;
    const int quad = l >> 4;
    const int row0 = blockIdx.x * RPB;   // 512 blocks, 32 rows each

    const short* __restrict__ W2S = wt + 32768;
    const short* __restrict__ WES = wt + 65536;

    // ---- x -> A-fragments for both row-tiles (verified R9/R10) ----
    short8 a1[2][4];
#pragma unroll
    for (int rt = 0; rt < 2; ++rt)
#pragma unroll
    for (int k = 0; k < 4; ++k) {
        const float* p = x + (size_t)(row0 + rt * 16 + l15) * 128 + k * 32 + quad * 8;
        const float4 v0 = *(const float4*)p;
        const float4 v1 = *(const float4*)(p + 4);
        short8 a;
        a[0] = f2bf(v0.x); a[1] = f2bf(v0.y); a[2] = f2bf(v0.z); a[3] = f2bf(v0.w);
        a[4] = f2bf(v1.x); a[5] = f2bf(v1.y); a[6] = f2bf(v1.z); a[7] = f2bf(v1.w);
        a1[rt][k] = a;
    }

    // ---- stage 1: h1 = relu(X @ W1n + b1n) ----
    // Each weight fragment loaded ONCE, fed to both row-tiles' MFMAs.
#pragma unroll
    for (int ci = 0; ci < 4; ++ci) {
        const int ct = 4 * w + ci;
        const float b = b1n[ct * 16 + l15];
        floatx4 acc0 = (floatx4){b, b, b, b};
        floatx4 acc1 = acc0;
#pragma unroll
        for (int k = 0; k < 4; ++k) {
            const short8 bf = *(const short8*)(wt + ((ct * 4 + k) * 64 + l) * 8);
            acc0 = __builtin_amdgcn_mfma_f32_16x16x32_bf16(a1[0][k], bf, acc0, 0, 0, 0);
            acc1 = __builtin_amdgcn_mfma_f32_16x16x32_bf16(a1[1][k], bf, acc1, 0, 0, 0);
        }
#pragma unroll
        for (int r = 0; r < 4; ++r) {
            h1s[(quad * 4 + r) * H1_STRIDE + ct * 16 + l15] = f2bf(fmaxf(acc0[r], 0.f));
            h1s[(16 + quad * 4 + r) * H1_STRIDE + ct * 16 + l15] = f2bf(fmaxf(acc1[r], 0.f));
        }
    }
    __syncthreads();

    // ---- stage 2: h = h1 @ W2n + b2n ----
    short8 a2[2][8];   // 64 VGPR — the register peak of the kernel
#pragma unroll
    for (int rt = 0; rt < 2; ++rt)
#pragma unroll
    for (int k = 0; k < 8; ++k)
        a2[rt][k] = *(const short8*)&h1s[(rt * 16 + l15) * H1_STRIDE + k * 32 + quad * 8];

#pragma unroll
    for (int ci = 0; ci < 2; ++ci) {
        const int ct = 2 * w + ci;
        const float b = b2n[ct * 16 + l15];
        floatx4 acc0 = (floatx4){b, b, b, b};
        floatx4 acc1 = acc0;
#pragma unroll
        for (int k = 0; k < 8; ++k) {
            const short8 bf = *(const short8*)(W2S + ((ct * 8 + k) * 64 + l) * 8);
            acc0 = __builtin_amdgcn_mfma_f32_16x16x32_bf16(a2[0][k], bf, acc0, 0, 0, 0);
            acc1 = __builtin_amdgcn_mfma_f32_16x16x32_bf16(a2[1][k], bf, acc1, 0, 0, 0);
        }
#pragma unroll
        for (int r = 0; r < 4; ++r) {
            const int row = quad * 4 + r;
            h_out[(size_t)(row0 + row) * 128 + ct * 16 + l15] = acc0[r];
            h_out[(size_t)(row0 + 16 + row) * 128 + ct * 16 + l15] = acc1[r];
            hbs[row * HB_STRIDE + ct * 16 + l15] = f2bf(acc0[r]);
            hbs[(16 + row) * HB_STRIDE + ct * 16 + l15] = f2bf(acc1[r]);
        }
    }
    __syncthreads();

    // ---- stage 3+4: t1 = relu(h @ WE + b1e); e = (t1 . w2e + b2e)/2048 ----
    short8 a3[2][4];
#pragma unroll
    for (int rt = 0; rt < 2; ++rt)
#pragma unroll
    for (int k = 0; k < 4; ++k)
        a3[rt][k] = *(const short8*)&hbs[(rt * 16 + l15) * HB_STRIDE + k * 32 + quad * 8];

    float p0[4] = {0.f, 0.f, 0.f, 0.f};
    float p1[4] = {0.f, 0.f, 0.f, 0.f};
#pragma unroll
    for (int ci = 0; ci < 2; ++ci) {
        const int ct = 2 * w + ci;
        const float b = b1e[ct * 16 + l15];
        floatx4 acc0 = (floatx4){b, b, b, b};
        floatx4 acc1 = acc0;
#pragma unroll
        for (int k = 0; k < 4; ++k) {
            const short8 bf = *(const short8*)(WES + ((ct * 4 + k) * 64 + l) * 8);
            acc0 = __builtin_amdgcn_mfma_f32_16x16x32_bf16(a3[0][k], bf, acc0, 0, 0, 0);
            acc1 = __builtin_amdgcn_mfma_f32_16x16x32_bf16(a3[1][k], bf, acc1, 0, 0, 0);
        }
        const float wv = w2e[ct * 16 + l15];
#pragma unroll
        for (int r = 0; r < 4; ++r) {
            p0[r] += fmaxf(acc0[r], 0.f) * wv;
            p1[r] += fmaxf(acc1[r], 0.f) * wv;
        }
    }
#pragma unroll
    for (int off = 8; off >= 1; off >>= 1)
#pragma unroll
        for (int r = 0; r < 4; ++r) {
            p0[r] += __shfl_xor(p0[r], off, 64);
            p1[r] += __shfl_xor(p1[r], off, 64);
        }
    if (l15 == 0) {
#pragma unroll
        for (int r = 0; r < 4; ++r) {
            partial[w][quad * 4 + r] = p0[r];
            partial[w][16 + quad * 4 + r] = p1[r];
        }
    }
    __syncthreads();
    if (t < RPB) {
        e_ws[row0 + t] = (partial[0][t] + partial[1][t] + partial[2][t]
                          + partial[3][t] + b2e[0]) * (1.0f / 2048.0f);
    }
}

// ---- pure streaming broadcast: 2048 blocks x 256 thr, 2 rows (16KB) per
// block, 4 coalesced float4 stores/thread -- the proven fill shape. ----
__global__ __launch_bounds__(256)
void edge_broadcast(const float* __restrict__ es, float* __restrict__ edge_out)
{
    const int t = threadIdx.x;
    const int r0 = blockIdx.x * 2;
    const float v0 = es[r0];          // block-uniform -> scalar loads
    const float v1 = es[r0 + 1];
    floatx4* __restrict__ e4 = (floatx4*)(edge_out + (size_t)r0 * 2048);
    const floatx4 a = (floatx4){v0, v0, v0, v0};
    const floatx4 b = (floatx4){v1, v1, v1, v1};
    e4[t] = a;
    e4[t + 256] = a;
    e4[t + 512] = b;
    e4[t + 768] = b;
}

extern "C" void kernel_launch(void* const* d_in, const int* in_sizes, int n_in,
                              void* d_out, int out_size, void* d_ws, size_t ws_size,
                              hipStream_t stream) {
    const float* x   = (const float*)d_in[0];
    const float* w1n = (const float*)d_in[1];
    const float* b1n = (const float*)d_in[2];
    const float* w2n = (const float*)d_in[3];
    const float* b2n = (const float*)d_in[4];
    const float* w1e = (const float*)d_in[5];
    const float* b1e = (const float*)d_in[6];
    const float* w2e = (const float*)d_in[7];
    const float* b2e = (const float*)d_in[8];

    float* h_out    = (float*)d_out;                              // (8,2048,128)
    float* edge_out = (float*)d_out + (size_t)8 * 2048 * 128;     // (8,2048,2048)
    short* wt       = (short*)d_ws;                               // 160 KB swizzled bf16 weights
    float* e_ws     = (float*)((char*)d_ws + 163840);             // 64 KB e scalars

    prep_weights<<<dim3(320), dim3(256), 0, stream>>>(w1n, w2n, w1e, wt);
    node_compute<<<dim3(512), dim3(TPB), 0, stream>>>(
        x, b1n, b2n, b1e, w2e, b2e, wt, h_out, e_ws);
    edge_broadcast<<<dim3(2048), dim3(256), 0, stream>>>(e_ws, edge_out);
}